// Round 1
// baseline (584.644 us; speedup 1.0000x reference)
//
#include <hip/hip_runtime.h>
#include <stdint.h>

#define BS  2
#define SEQ 512
#define D   128
#define NH  8
#define DH  16

typedef float f32x4 __attribute__((ext_vector_type(4)));
typedef short bf16x8 __attribute__((ext_vector_type(8)));

__device__ __forceinline__ uint16_t f2bf(float x) {
    union { float f; uint32_t u; } v; v.f = x;
    uint32_t r = v.u + 0x7FFFu + ((v.u >> 16) & 1u);
    return (uint16_t)(r >> 16);
}

union BF8 { bf16x8 v; uint16_t u[8]; uint32_t w[4]; };

// ---------------- Kernel 1: Q,K,V,Ani,Anj = h @ W^T (5 small GEMMs) ----------
__global__ __launch_bounds__(128) void proj5_kernel(
    const float* __restrict__ h,
    const float* __restrict__ Wq, const float* __restrict__ Wk,
    const float* __restrict__ Wv, const float* __restrict__ Wni,
    const float* __restrict__ Wnj,
    float* __restrict__ Q, float* __restrict__ K, float* __restrict__ V,
    float* __restrict__ Ani, float* __restrict__ Anj)
{
    __shared__ float hs[4][D];
    int t = threadIdx.x;            // t = output dim d
    int rb = blockIdx.x * 4;        // 4 rows of flattened (b*SEQ+i)
    for (int r = 0; r < 4; ++r) hs[r][t] = h[(size_t)(rb + r) * D + t];
    __syncthreads();

    float aq[4] = {0,0,0,0}, ak[4] = {0,0,0,0}, av[4] = {0,0,0,0};
    float ai[4] = {0,0,0,0}, aj[4] = {0,0,0,0};
    for (int c = 0; c < D; c += 4) {
        f32x4 wq = *(const f32x4*)(Wq  + t * D + c);
        f32x4 wk = *(const f32x4*)(Wk  + t * D + c);
        f32x4 wv = *(const f32x4*)(Wv  + t * D + c);
        f32x4 wi = *(const f32x4*)(Wni + t * D + c);
        f32x4 wj = *(const f32x4*)(Wnj + t * D + c);
        #pragma unroll
        for (int r = 0; r < 4; ++r) {
            f32x4 hv = *(const f32x4*)(&hs[r][c]);
            aq[r] += wq.x*hv.x + wq.y*hv.y + wq.z*hv.z + wq.w*hv.w;
            ak[r] += wk.x*hv.x + wk.y*hv.y + wk.z*hv.z + wk.w*hv.w;
            av[r] += wv.x*hv.x + wv.y*hv.y + wv.z*hv.z + wv.w*hv.w;
            ai[r] += wi.x*hv.x + wi.y*hv.y + wi.z*hv.z + wi.w*hv.w;
            aj[r] += wj.x*hv.x + wj.y*hv.y + wj.z*hv.z + wj.w*hv.w;
        }
    }
    for (int r = 0; r < 4; ++r) {
        size_t o = (size_t)(rb + r) * D + t;
        Q[o] = aq[r]; K[o] = ak[r]; V[o] = av[r]; Ani[o] = ai[r]; Anj[o] = aj[r];
    }
}

// ---------------- Kernel 2: edge GEMM + epilogue (edge_out + scores) ---------
// grid: (BS*SEQ) * (SEQ/128) blocks; block = 512 threads (8 waves)
// wave w: d-group = (w&3)*32, j-group = (w>>2)*64; per-wave output 64j x 32d
__global__ __launch_bounds__(512) void edge_kernel(
    const float* __restrict__ e, const float* __restrict__ We,
    const float* __restrict__ Q, const float* __restrict__ Kn,
    const float* __restrict__ Ani, const float* __restrict__ Anj,
    float* __restrict__ edge_out, float* __restrict__ scores)
{
    __shared__ __align__(16) unsigned char lds_e[128 * 256];  // 128 rows x 128 bf16 (swizzled)
    int t  = threadIdx.x;
    int bi = blockIdx.x >> 2;            // b*SEQ + i
    int b  = bi >> 9;
    int i  = bi & (SEQ - 1);
    int j0 = (blockIdx.x & 3) * 128;

    // ---- stage e tile (128 j x 128 c) fp32 -> bf16 LDS, XOR-swizzled ----
    const float* ebase = e + ((size_t)bi * SEQ + j0) * D;
    #pragma unroll
    for (int it = 0; it < 8; ++it) {
        int idx = it * 2048 + t * 4;
        int r = idx >> 7;
        int c = idx & 127;
        f32x4 v4 = *(const f32x4*)(ebase + idx);
        uint32_t lo = (uint32_t)f2bf(v4.x) | ((uint32_t)f2bf(v4.y) << 16);
        uint32_t hi = (uint32_t)f2bf(v4.z) | ((uint32_t)f2bf(v4.w) << 16);
        int byte = r * 256 + ((((c >> 3)) ^ (r & 7)) << 4) + ((c & 4) << 1);
        *(uint32_t*)(lds_e + byte)     = lo;
        *(uint32_t*)(lds_e + byte + 4) = hi;
    }

    int w = t >> 6, lane = t & 63;
    int ln15 = lane & 15, lhi = lane >> 4;
    int dg = (w & 3) * 32;
    int jg = (w >> 2) * 64;

    // ---- preload B fragments (We, row d x col c) from L2, fp32 -> bf16 ----
    BF8 bfr[2][4];
    #pragma unroll
    for (int dt2 = 0; dt2 < 2; ++dt2) {
        int drow = dg + dt2 * 16 + ln15;
        #pragma unroll
        for (int kk = 0; kk < 4; ++kk) {
            int coff = kk * 32 + lhi * 8;
            f32x4 w0 = *(const f32x4*)(We + drow * D + coff);
            f32x4 w1 = *(const f32x4*)(We + drow * D + coff + 4);
            BF8 bb;
            bb.w[0] = (uint32_t)f2bf(w0.x) | ((uint32_t)f2bf(w0.y) << 16);
            bb.w[1] = (uint32_t)f2bf(w0.z) | ((uint32_t)f2bf(w0.w) << 16);
            bb.w[2] = (uint32_t)f2bf(w1.x) | ((uint32_t)f2bf(w1.y) << 16);
            bb.w[3] = (uint32_t)f2bf(w1.z) | ((uint32_t)f2bf(w1.w) << 16);
            bfr[dt2][kk] = bb;
        }
    }

    __syncthreads();

    // ---- MFMA: EV = e @ We^T for this wave's 64j x 32d tile ----
    f32x4 acc[4][2];
    #pragma unroll
    for (int jt = 0; jt < 4; ++jt)
        #pragma unroll
        for (int dt2 = 0; dt2 < 2; ++dt2)
            acc[jt][dt2] = (f32x4){0.f, 0.f, 0.f, 0.f};

    #pragma unroll
    for (int kk = 0; kk < 4; ++kk) {
        BF8 a[4];
        #pragma unroll
        for (int jt = 0; jt < 4; ++jt) {
            int r = jg + jt * 16 + ln15;
            int g = kk * 4 + lhi;
            int byte = r * 256 + ((g ^ (r & 7)) << 4);
            a[jt].v = *(const bf16x8*)(lds_e + byte);
        }
        #pragma unroll
        for (int jt = 0; jt < 4; ++jt)
            #pragma unroll
            for (int dt2 = 0; dt2 < 2; ++dt2)
                acc[jt][dt2] = __builtin_amdgcn_mfma_f32_16x16x32_bf16(
                    a[jt].v, bfr[dt2][kk].v, acc[jt][dt2], 0, 0, 0);
    }

    // ---- epilogue: +Ani +Anj, store edge_out, scores via 16-lane reduce ----
    const float* qrow   = Q   + (size_t)bi * D;
    const float* anirow = Ani + (size_t)bi * D;
    float qv[2], aiv[2];
    #pragma unroll
    for (int dt2 = 0; dt2 < 2; ++dt2) {
        qv[dt2]  = qrow[dg + dt2 * 16 + ln15];
        aiv[dt2] = anirow[dg + dt2 * 16 + ln15];
    }
    float* eout = edge_out + ((size_t)bi * SEQ + j0) * D;

    #pragma unroll
    for (int jt = 0; jt < 4; ++jt) {
        #pragma unroll
        for (int dt2 = 0; dt2 < 2; ++dt2) {
            int dcol = dg + dt2 * 16 + ln15;
            int head = (dg >> 4) + dt2;
            #pragma unroll
            for (int r = 0; r < 4; ++r) {
                int jrel = jg + jt * 16 + lhi * 4 + r;   // 0..127 within tile
                int j = j0 + jrel;
                size_t bjd = ((size_t)b * SEQ + j) * D + dcol;
                float ev = acc[jt][dt2][r] + aiv[dt2] + Anj[bjd];
                eout[(size_t)jrel * D + dcol] = ev;
                float s = ev * qv[dt2] * Kn[bjd];
                s += __shfl_xor(s, 1);
                s += __shfl_xor(s, 2);
                s += __shfl_xor(s, 4);
                s += __shfl_xor(s, 8);
                if (ln15 == 0)
                    scores[((size_t)(b * NH + head) * SEQ + i) * SEQ + j] = s * 0.25f;
            }
        }
    }
}

// ---------------- Kernel 3: softmax over j + PV ------------------------------
// wave per (b,h,i) row; 4 waves/block
__global__ __launch_bounds__(256) void softmax_pv_kernel(
    const float* __restrict__ scores, const float* __restrict__ V,
    float* __restrict__ out)
{
    __shared__ float p_lds[4][SEQ];
    int widx = threadIdx.x >> 6;
    int lane = threadIdx.x & 63;
    int row = blockIdx.x * 4 + widx;     // (b*NH + h)*SEQ + i
    int i  = row & (SEQ - 1);
    int bh = row >> 9;
    int b  = bh >> 3, hh = bh & 7;

    const float* srow = scores + (size_t)row * SEQ;
    f32x4 s0 = *(const f32x4*)(srow + lane * 4);
    f32x4 s1 = *(const f32x4*)(srow + 256 + lane * 4);

    float m = fmaxf(fmaxf(fmaxf(s0.x, s0.y), fmaxf(s0.z, s0.w)),
                    fmaxf(fmaxf(s1.x, s1.y), fmaxf(s1.z, s1.w)));
    #pragma unroll
    for (int off = 1; off < 64; off <<= 1) m = fmaxf(m, __shfl_xor(m, off));

    float p[8];
    p[0] = __expf(s0.x - m); p[1] = __expf(s0.y - m);
    p[2] = __expf(s0.z - m); p[3] = __expf(s0.w - m);
    p[4] = __expf(s1.x - m); p[5] = __expf(s1.y - m);
    p[6] = __expf(s1.z - m); p[7] = __expf(s1.w - m);
    float sum = ((p[0]+p[1])+(p[2]+p[3])) + ((p[4]+p[5])+(p[6]+p[7]));
    #pragma unroll
    for (int off = 1; off < 64; off <<= 1) sum += __shfl_xor(sum, off);
    float inv = 1.0f / sum;

    f32x4 o0 = {p[0]*inv, p[1]*inv, p[2]*inv, p[3]*inv};
    f32x4 o1 = {p[4]*inv, p[5]*inv, p[6]*inv, p[7]*inv};
    *(f32x4*)(&p_lds[widx][lane * 4])       = o0;
    *(f32x4*)(&p_lds[widx][256 + lane * 4]) = o1;
    __syncthreads();

    int dh = lane & 15, g = lane >> 4;
    const float* vbase = V + (size_t)b * SEQ * D + hh * DH + dh;
    float a = 0.f;
    #pragma unroll 4
    for (int jj = 0; jj < SEQ / 4; ++jj) {
        int j = jj * 4 + g;
        a += p_lds[widx][j] * vbase[(size_t)j * D];
    }
    a += __shfl_xor(a, 16);
    a += __shfl_xor(a, 32);
    if (lane < 16)
        out[((size_t)b * SEQ + i) * D + hh * DH + lane] = a;
}

// ---------------- launch -----------------------------------------------------
extern "C" void kernel_launch(void* const* d_in, const int* in_sizes, int n_in,
                              void* d_out, int out_size, void* d_ws, size_t ws_size,
                              hipStream_t stream)
{
    const float* h   = (const float*)d_in[0];
    const float* e   = (const float*)d_in[1];
    const float* Wq  = (const float*)d_in[2];
    const float* Wk  = (const float*)d_in[3];
    const float* Wv  = (const float*)d_in[4];
    const float* We  = (const float*)d_in[5];
    const float* Wni = (const float*)d_in[6];
    const float* Wnj = (const float*)d_in[7];

    float* out      = (float*)d_out;                    // BS*SEQ*D
    float* edge_out = out + (size_t)BS * SEQ * D;       // BS*SEQ*SEQ*D

    float* ws = (float*)d_ws;
    const size_t ROWD = (size_t)BS * SEQ * D;           // 131072
    float* Q      = ws;
    float* K      = ws + ROWD;
    float* V      = ws + ROWD * 2;
    float* Ani    = ws + ROWD * 3;
    float* Anj    = ws + ROWD * 4;
    float* scores = ws + ROWD * 5;                      // BS*NH*SEQ*SEQ floats

    proj5_kernel<<<BS * SEQ / 4, 128, 0, stream>>>(h, Wq, Wk, Wv, Wni, Wnj,
                                                   Q, K, V, Ani, Anj);
    edge_kernel<<<BS * SEQ * (SEQ / 128), 512, 0, stream>>>(e, We, Q, K, Ani, Anj,
                                                            edge_out, scores);
    softmax_pv_kernel<<<BS * NH * SEQ / 4, 256, 0, stream>>>(scores, V, out);
}